// Round 3
// baseline (467.439 us; speedup 1.0000x reference)
//
#include <hip/hip_runtime.h>

typedef unsigned short u16;
typedef short bf16x8 __attribute__((ext_vector_type(8)));
typedef float f32x4 __attribute__((ext_vector_type(4)));

#define D_IN 2048
#define H_DIM 2048
#define K_CH 4096

__device__ __forceinline__ u16 f2bf(float f) {
  unsigned int u = __float_as_uint(f);
  u += 0x7fffu + ((u >> 16) & 1u);   // round-to-nearest-even
  return (u16)(u >> 16);
}
__device__ __forceinline__ float sigmoidf(float x) {
  return 1.0f / (1.0f + __expf(-x));
}
__device__ __forceinline__ uint2 pack8(float4 a, float4 b) {
  uint2 r;
  r.x = (unsigned)f2bf(a.x) | ((unsigned)f2bf(a.y) << 16);
  r.y = (unsigned)f2bf(a.z) | ((unsigned)f2bf(a.w) << 16);
  (void)b;
  return r;
}

// ---------------------------------------------------------------------------
// Kernel A (fused prep):
//  blocks 0..1023:  hsum[h] += sum of 4 rows of children_h; chb = bf16(children_h)
//                   row loop fully unrolled -> 8 independent 16B loads in flight
//  blocks 1024..1535: wfhb = bf16(W_fh), 8192 elems/block, unrolled x4
// ---------------------------------------------------------------------------
__global__ __launch_bounds__(256) void kprep(const float* __restrict__ ch,
                                             const float* __restrict__ wfh,
                                             float* __restrict__ hsum,
                                             u16* __restrict__ chb,
                                             u16* __restrict__ wfhb) {
  const int t = threadIdx.x;
  if (blockIdx.x < 1024) {
    const int r0 = blockIdx.x * 4;
    float4 a[4], b[4];
#pragma unroll
    for (int r = 0; r < 4; ++r) {
      const float4* p = (const float4*)(ch + (size_t)(r0 + r) * H_DIM + t * 8);
      a[r] = p[0];
      b[r] = p[1];
    }
    float s0 = 0.f, s1 = 0.f, s2 = 0.f, s3 = 0.f;
    float s4 = 0.f, s5 = 0.f, s6 = 0.f, s7 = 0.f;
#pragma unroll
    for (int r = 0; r < 4; ++r) {
      s0 += a[r].x; s1 += a[r].y; s2 += a[r].z; s3 += a[r].w;
      s4 += b[r].x; s5 += b[r].y; s6 += b[r].z; s7 += b[r].w;
      uint4 w;
      w.x = (unsigned)f2bf(a[r].x) | ((unsigned)f2bf(a[r].y) << 16);
      w.y = (unsigned)f2bf(a[r].z) | ((unsigned)f2bf(a[r].w) << 16);
      w.z = (unsigned)f2bf(b[r].x) | ((unsigned)f2bf(b[r].y) << 16);
      w.w = (unsigned)f2bf(b[r].z) | ((unsigned)f2bf(b[r].w) << 16);
      *(uint4*)(chb + (size_t)(r0 + r) * H_DIM + t * 8) = w;
    }
    float* p = hsum + t * 8;
    atomicAdd(p + 0, s0); atomicAdd(p + 1, s1);
    atomicAdd(p + 2, s2); atomicAdd(p + 3, s3);
    atomicAdd(p + 4, s4); atomicAdd(p + 5, s5);
    atomicAdd(p + 6, s6); atomicAdd(p + 7, s7);
  } else {
    const size_t base = (size_t)(blockIdx.x - 1024) * 8192 + t * 8;
    float4 a[4], b[4];
#pragma unroll
    for (int i = 0; i < 4; ++i) {
      const float4* p = (const float4*)(wfh + base + i * 2048);
      a[i] = p[0];
      b[i] = p[1];
    }
#pragma unroll
    for (int i = 0; i < 4; ++i) {
      uint4 w;
      w.x = (unsigned)f2bf(a[i].x) | ((unsigned)f2bf(a[i].y) << 16);
      w.y = (unsigned)f2bf(a[i].z) | ((unsigned)f2bf(a[i].w) << 16);
      w.z = (unsigned)f2bf(b[i].x) | ((unsigned)f2bf(b[i].y) << 16);
      w.w = (unsigned)f2bf(b[i].z) | ((unsigned)f2bf(b[i].w) << 16);
      *(uint4*)(wfhb + base + i * 2048) = w;
    }
  }
}

// ---------------------------------------------------------------------------
// Kernel B: one wave per output row, fp32.
//   rows 0..6143   : iou[row] = W_iou_x[row]@x + b_iou_x + W_iou_h[row]@h_sum + b_iou_h
//   rows 6144..8191: g[h] = W_fx[h]@x + b_fx[h] + b_fh[h]
// ---------------------------------------------------------------------------
__global__ __launch_bounds__(256) void kmatvec(
    const float* __restrict__ Wix, const float* __restrict__ bix,
    const float* __restrict__ Wih, const float* __restrict__ bih,
    const float* __restrict__ Wfx, const float* __restrict__ bfx,
    const float* __restrict__ bfh, const float* __restrict__ x,
    const float* __restrict__ hsum, float* __restrict__ iou,
    float* __restrict__ g) {
  const int wave = threadIdx.x >> 6, lane = threadIdx.x & 63;
  const int row = blockIdx.x * 4 + wave;  // 0..8191
  float s = 0.f;
  if (row < 6144) {
    const float4* wx = (const float4*)(Wix + (size_t)row * D_IN);
    const float4* wh = (const float4*)(Wih + (size_t)row * H_DIM);
    const float4* xv = (const float4*)x;
    const float4* hv = (const float4*)hsum;
#pragma unroll
    for (int i = 0; i < 8; ++i) {
      int idx = i * 64 + lane;
      float4 a = wx[idx], b = xv[idx];
      s += a.x * b.x + a.y * b.y + a.z * b.z + a.w * b.w;
      float4 c = wh[idx], d = hv[idx];
      s += c.x * d.x + c.y * d.y + c.z * d.z + c.w * d.w;
    }
#pragma unroll
    for (int off = 32; off > 0; off >>= 1) s += __shfl_xor(s, off);
    if (lane == 0) iou[row] = s + bix[row] + bih[row];
  } else {
    const int h = row - 6144;
    const float4* w = (const float4*)(Wfx + (size_t)h * D_IN);
    const float4* xv = (const float4*)x;
#pragma unroll
    for (int i = 0; i < 8; ++i) {
      int idx = i * 64 + lane;
      float4 a = w[idx], b = xv[idx];
      s += a.x * b.x + a.y * b.y + a.z * b.z + a.w * b.w;
    }
#pragma unroll
    for (int off = 32; off > 0; off >>= 1) s += __shfl_xor(s, off);
    if (lane == 0) g[h] = s + bfx[h] + bfh[h];
  }
}

// ---------------------------------------------------------------------------
// Kernel C: fused bf16 GEMM + sigmoid + weighted K-reduction.
//   fh[k,h] = chb[k,:] @ wfhb[h,:]   (A.B^T, row-major, inner=2048)
//   acc[h] += sum_k sigmoid(g[h] + fh[k,h]) * children_c[k,h]  (cc fp32)
// 128x128 tile, BK=32, 4 waves (2x2 of 64x64), 16B global_load_lds staging,
// 16x16x32 bf16 MFMA, 4x4 accumulators/wave.
// ---------------------------------------------------------------------------
#define BM 128
#define BN 128
#define BK 32

__global__ __launch_bounds__(256) void kgemm(
    const u16* __restrict__ chb, const float* __restrict__ cc,
    const u16* __restrict__ wfhb, const float* __restrict__ g,
    float* __restrict__ accv) {
  __shared__ u16 As[BM * BK];
  __shared__ u16 Bs[BN * BK];

  const int t = threadIdx.x;
  const int wave = t >> 6, lane = t & 63;
  const int lrow = lane & 15, lquad = lane >> 4;
  const int wm = wave >> 1, wn = wave & 1;
  const int row0 = blockIdx.x * BM;  // children tile base (32 tiles)
  const int col0 = blockIdx.y * BN;  // h tile base (16 tiles)

  f32x4 acc[4][4] = {};

  const int stage_row = t >> 2;      // 0..63
  const int stage_k = (t & 3) * 8;   // 0,8,16,24

  for (int kb = 0; kb < D_IN / BK; ++kb) {
    __syncthreads();
    const u16* ag = chb  + (size_t)(row0 + stage_row) * H_DIM + kb * BK + stage_k;
    const u16* bg = wfhb + (size_t)(col0 + stage_row) * H_DIM + kb * BK + stage_k;
    __builtin_amdgcn_global_load_lds(
        (const __attribute__((address_space(1))) void*)ag,
        (__attribute__((address_space(3))) void*)(As + wave * 512), 16, 0, 0);
    __builtin_amdgcn_global_load_lds(
        (const __attribute__((address_space(1))) void*)(ag + (size_t)64 * H_DIM),
        (__attribute__((address_space(3))) void*)(As + 2048 + wave * 512), 16, 0, 0);
    __builtin_amdgcn_global_load_lds(
        (const __attribute__((address_space(1))) void*)bg,
        (__attribute__((address_space(3))) void*)(Bs + wave * 512), 16, 0, 0);
    __builtin_amdgcn_global_load_lds(
        (const __attribute__((address_space(1))) void*)(bg + (size_t)64 * H_DIM),
        (__attribute__((address_space(3))) void*)(Bs + 2048 + wave * 512), 16, 0, 0);
    __syncthreads();

    bf16x8 fragA[4], fragB[4];
#pragma unroll
    for (int i = 0; i < 4; ++i)
      fragA[i] = *(const bf16x8*)(As + (wm * 64 + i * 16 + lrow) * BK + lquad * 8);
#pragma unroll
    for (int i = 0; i < 4; ++i)
      fragB[i] = *(const bf16x8*)(Bs + (wn * 64 + i * 16 + lrow) * BK + lquad * 8);
#pragma unroll
    for (int mi = 0; mi < 4; ++mi)
#pragma unroll
      for (int ni = 0; ni < 4; ++ni)
        acc[mi][ni] = __builtin_amdgcn_mfma_f32_16x16x32_bf16(
            fragA[mi], fragB[ni], acc[mi][ni], 0, 0, 0);
  }

  // Epilogue. C/D layout: col = lane&15, row = (lane>>4)*4 + reg.
#pragma unroll
  for (int ni = 0; ni < 4; ++ni) {
    const int colg = col0 + wn * 64 + ni * 16 + lrow;
    const float gv = g[colg];
    float s = 0.f;
#pragma unroll
    for (int mi = 0; mi < 4; ++mi) {
      const int rowg = row0 + wm * 64 + mi * 16 + lquad * 4;
#pragma unroll
      for (int r = 0; r < 4; ++r) {
        float f = sigmoidf(gv + acc[mi][ni][r]);
        s += f * cc[(size_t)(rowg + r) * H_DIM + colg];
      }
    }
    s += __shfl_xor(s, 16);
    s += __shfl_xor(s, 32);
    if (lquad == 0) atomicAdd(accv + colg, s);
  }
}

// ---------------------------------------------------------------------------
// Kernel D: finalize (fp32 out).  iou = [i|o|u]; c = sig(i)*tanh(u) + acc;
// h = sig(o)*tanh(c).  out = [sig(o) | c | h].
// ---------------------------------------------------------------------------
__global__ __launch_bounds__(256) void kfinal(const float* __restrict__ iou,
                                              const float* __restrict__ accv,
                                              float* __restrict__ out) {
  const int h = blockIdx.x * 256 + threadIdx.x;
  float si = sigmoidf(iou[h]);
  float so = sigmoidf(iou[H_DIM + h]);
  float tu = tanhf(iou[2 * H_DIM + h]);
  float c = si * tu + accv[h];
  float hh = so * tanhf(c);
  out[h] = so;
  out[H_DIM + h] = c;
  out[2 * H_DIM + h] = hh;
}

extern "C" void kernel_launch(void* const* d_in, const int* in_sizes, int n_in,
                              void* d_out, int out_size, void* d_ws, size_t ws_size,
                              hipStream_t stream) {
  const float* x   = (const float*)d_in[0];   // input [2048]
  const float* cc  = (const float*)d_in[1];   // children_c [4096,2048]
  const float* ch  = (const float*)d_in[2];   // children_h [4096,2048]
  const float* Wix = (const float*)d_in[3];   // W_iou_x [6144,2048]
  const float* bix = (const float*)d_in[4];   // b_iou_x [6144]
  const float* Wih = (const float*)d_in[5];   // W_iou_h [6144,2048]
  const float* bih = (const float*)d_in[6];   // b_iou_h [6144]
  const float* Wfx = (const float*)d_in[7];   // W_fx [2048,2048]
  const float* bfx = (const float*)d_in[8];   // b_fx [2048]
  const float* Wfh = (const float*)d_in[9];   // W_fh [2048,2048]
  const float* bfh = (const float*)d_in[10];  // b_fh [2048]

  float* ws   = (float*)d_ws;
  float* hsum = ws;            // [2048]
  float* iou  = ws + 2048;     // [6144]
  float* g    = ws + 8192;     // [2048]
  float* accv = ws + 10240;    // [2048]
  u16* chb  = (u16*)(ws + 12288);            // [4096*2048] bf16
  u16* wfhb = chb + (size_t)K_CH * H_DIM;    // [2048*2048] bf16
  float* out = (float*)d_out;

  hipMemsetAsync(d_ws, 0, 12288 * sizeof(float), stream);
  kprep<<<1536, 256, 0, stream>>>(ch, Wfh, hsum, chb, wfhb);
  kmatvec<<<2048, 256, 0, stream>>>(Wix, bix, Wih, bih, Wfx, bfx, bfh, x, hsum, iou, g);
  kgemm<<<dim3(32, 16), 256, 0, stream>>>(chb, cc, wfhb, g, accv);
  kfinal<<<8, 256, 0, stream>>>(iou, accv, out);
}

// Round 4
// 292.005 us; speedup vs baseline: 1.6008x; 1.6008x over previous
//
#include <hip/hip_runtime.h>

typedef unsigned short u16;
typedef short bf16x8 __attribute__((ext_vector_type(8)));
typedef float f32x4 __attribute__((ext_vector_type(4)));

#define D_IN 2048
#define H_DIM 2048
#define K_CH 4096

__device__ __forceinline__ u16 f2bf(float f) {
  unsigned int u = __float_as_uint(f);
  u += 0x7fffu + ((u >> 16) & 1u);   // round-to-nearest-even
  return (u16)(u >> 16);
}
__device__ __forceinline__ float sigmoidf(float x) {
  return 1.0f / (1.0f + __expf(-x));
}
__device__ __forceinline__ uint4 packrow(float4 a, float4 b) {
  uint4 w;
  w.x = (unsigned)f2bf(a.x) | ((unsigned)f2bf(a.y) << 16);
  w.y = (unsigned)f2bf(a.z) | ((unsigned)f2bf(a.w) << 16);
  w.z = (unsigned)f2bf(b.x) | ((unsigned)f2bf(b.y) << 16);
  w.w = (unsigned)f2bf(b.z) | ((unsigned)f2bf(b.w) << 16);
  return w;
}

// ---------------------------------------------------------------------------
// Kernel A (prep, NO atomics):
//  blocks 0..255:  16 rows of children_h each: column-sum into registers +
//                  bf16-convert; per-block partial sums -> partials[block][2048]
//  blocks 256..511: wfhb = bf16(W_fh), 16384 elems/block, 8 loads in flight
// ---------------------------------------------------------------------------
__global__ __launch_bounds__(256) void kprep(const float* __restrict__ ch,
                                             const float* __restrict__ wfh,
                                             float* __restrict__ partials,
                                             u16* __restrict__ chb,
                                             u16* __restrict__ wfhb) {
  const int t = threadIdx.x;
  if (blockIdx.x < 256) {
    const int r0 = blockIdx.x * 16;
    float s0 = 0.f, s1 = 0.f, s2 = 0.f, s3 = 0.f;
    float s4 = 0.f, s5 = 0.f, s6 = 0.f, s7 = 0.f;
#pragma unroll
    for (int gq = 0; gq < 4; ++gq) {
      float4 a[4], b[4];
#pragma unroll
      for (int r = 0; r < 4; ++r) {
        const float4* p =
            (const float4*)(ch + (size_t)(r0 + gq * 4 + r) * H_DIM + t * 8);
        a[r] = p[0];
        b[r] = p[1];
      }
#pragma unroll
      for (int r = 0; r < 4; ++r) {
        s0 += a[r].x; s1 += a[r].y; s2 += a[r].z; s3 += a[r].w;
        s4 += b[r].x; s5 += b[r].y; s6 += b[r].z; s7 += b[r].w;
        *(uint4*)(chb + (size_t)(r0 + gq * 4 + r) * H_DIM + t * 8) =
            packrow(a[r], b[r]);
      }
    }
    float4 lo, hi;
    lo.x = s0; lo.y = s1; lo.z = s2; lo.w = s3;
    hi.x = s4; hi.y = s5; hi.z = s6; hi.w = s7;
    float* pp = partials + (size_t)blockIdx.x * H_DIM + t * 8;
    *(float4*)pp = lo;
    *(float4*)(pp + 4) = hi;
  } else {
    const size_t base = (size_t)(blockIdx.x - 256) * 16384 + t * 8;
#pragma unroll
    for (int gq = 0; gq < 2; ++gq) {
      float4 a[4], b[4];
#pragma unroll
      for (int j = 0; j < 4; ++j) {
        const float4* p = (const float4*)(wfh + base + (gq * 4 + j) * 2048);
        a[j] = p[0];
        b[j] = p[1];
      }
#pragma unroll
      for (int j = 0; j < 4; ++j)
        *(uint4*)(wfhb + base + (gq * 4 + j) * 2048) = packrow(a[j], b[j]);
    }
  }
}

// ---------------------------------------------------------------------------
// Kernel A2: hsum[c] = sum_p partials[p][c].  8 blocks x 256 threads, one
// column per thread, 8 independent accumulators for MLP. ~2 MB read.
// ---------------------------------------------------------------------------
__global__ __launch_bounds__(256) void kred(const float* __restrict__ partials,
                                            float* __restrict__ hsum) {
  const int c = blockIdx.x * 256 + threadIdx.x;
  float acc0 = 0.f, acc1 = 0.f, acc2 = 0.f, acc3 = 0.f;
  float acc4 = 0.f, acc5 = 0.f, acc6 = 0.f, acc7 = 0.f;
  for (int p = 0; p < 256; p += 8) {
    acc0 += partials[(size_t)(p + 0) * H_DIM + c];
    acc1 += partials[(size_t)(p + 1) * H_DIM + c];
    acc2 += partials[(size_t)(p + 2) * H_DIM + c];
    acc3 += partials[(size_t)(p + 3) * H_DIM + c];
    acc4 += partials[(size_t)(p + 4) * H_DIM + c];
    acc5 += partials[(size_t)(p + 5) * H_DIM + c];
    acc6 += partials[(size_t)(p + 6) * H_DIM + c];
    acc7 += partials[(size_t)(p + 7) * H_DIM + c];
  }
  hsum[c] = ((acc0 + acc1) + (acc2 + acc3)) + ((acc4 + acc5) + (acc6 + acc7));
}

// ---------------------------------------------------------------------------
// Kernel B: one wave per output row, fp32.
//   rows 0..6143   : iou[row] = W_iou_x[row]@x + b_iou_x + W_iou_h[row]@h_sum + b_iou_h
//   rows 6144..8191: g[h] = W_fx[h]@x + b_fx[h] + b_fh[h]
// ---------------------------------------------------------------------------
__global__ __launch_bounds__(256) void kmatvec(
    const float* __restrict__ Wix, const float* __restrict__ bix,
    const float* __restrict__ Wih, const float* __restrict__ bih,
    const float* __restrict__ Wfx, const float* __restrict__ bfx,
    const float* __restrict__ bfh, const float* __restrict__ x,
    const float* __restrict__ hsum, float* __restrict__ iou,
    float* __restrict__ g) {
  const int wave = threadIdx.x >> 6, lane = threadIdx.x & 63;
  const int row = blockIdx.x * 4 + wave;  // 0..8191
  float s = 0.f;
  if (row < 6144) {
    const float4* wx = (const float4*)(Wix + (size_t)row * D_IN);
    const float4* wh = (const float4*)(Wih + (size_t)row * H_DIM);
    const float4* xv = (const float4*)x;
    const float4* hv = (const float4*)hsum;
#pragma unroll
    for (int i = 0; i < 8; ++i) {
      int idx = i * 64 + lane;
      float4 a = wx[idx], b = xv[idx];
      s += a.x * b.x + a.y * b.y + a.z * b.z + a.w * b.w;
      float4 c = wh[idx], d = hv[idx];
      s += c.x * d.x + c.y * d.y + c.z * d.z + c.w * d.w;
    }
#pragma unroll
    for (int off = 32; off > 0; off >>= 1) s += __shfl_xor(s, off);
    if (lane == 0) iou[row] = s + bix[row] + bih[row];
  } else {
    const int h = row - 6144;
    const float4* w = (const float4*)(Wfx + (size_t)h * D_IN);
    const float4* xv = (const float4*)x;
#pragma unroll
    for (int i = 0; i < 8; ++i) {
      int idx = i * 64 + lane;
      float4 a = w[idx], b = xv[idx];
      s += a.x * b.x + a.y * b.y + a.z * b.z + a.w * b.w;
    }
#pragma unroll
    for (int off = 32; off > 0; off >>= 1) s += __shfl_xor(s, off);
    if (lane == 0) g[h] = s + bfx[h] + bfh[h];
  }
}

// ---------------------------------------------------------------------------
// Kernel C: fused bf16 GEMM + sigmoid + weighted K-reduction.
//   fh[k,h] = chb[k,:] @ wfhb[h,:]   (A.B^T, row-major, inner=2048)
//   acc[h] += sum_k sigmoid(g[h] + fh[k,h]) * children_c[k,h]  (cc fp32)
// 128x128 tile, BK=32, 4 waves (2x2 of 64x64), 16B global_load_lds staging,
// 16x16x32 bf16 MFMA, 4x4 accumulators/wave.
// ---------------------------------------------------------------------------
#define BM 128
#define BN 128
#define BK 32

__global__ __launch_bounds__(256) void kgemm(
    const u16* __restrict__ chb, const float* __restrict__ cc,
    const u16* __restrict__ wfhb, const float* __restrict__ g,
    float* __restrict__ accv) {
  __shared__ u16 As[BM * BK];
  __shared__ u16 Bs[BN * BK];

  const int t = threadIdx.x;
  const int wave = t >> 6, lane = t & 63;
  const int lrow = lane & 15, lquad = lane >> 4;
  const int wm = wave >> 1, wn = wave & 1;
  const int row0 = blockIdx.x * BM;  // children tile base (32 tiles)
  const int col0 = blockIdx.y * BN;  // h tile base (16 tiles)

  f32x4 acc[4][4] = {};

  const int stage_row = t >> 2;      // 0..63
  const int stage_k = (t & 3) * 8;   // 0,8,16,24

  for (int kb = 0; kb < D_IN / BK; ++kb) {
    __syncthreads();
    const u16* ag = chb  + (size_t)(row0 + stage_row) * H_DIM + kb * BK + stage_k;
    const u16* bg = wfhb + (size_t)(col0 + stage_row) * H_DIM + kb * BK + stage_k;
    __builtin_amdgcn_global_load_lds(
        (const __attribute__((address_space(1))) void*)ag,
        (__attribute__((address_space(3))) void*)(As + wave * 512), 16, 0, 0);
    __builtin_amdgcn_global_load_lds(
        (const __attribute__((address_space(1))) void*)(ag + (size_t)64 * H_DIM),
        (__attribute__((address_space(3))) void*)(As + 2048 + wave * 512), 16, 0, 0);
    __builtin_amdgcn_global_load_lds(
        (const __attribute__((address_space(1))) void*)bg,
        (__attribute__((address_space(3))) void*)(Bs + wave * 512), 16, 0, 0);
    __builtin_amdgcn_global_load_lds(
        (const __attribute__((address_space(1))) void*)(bg + (size_t)64 * H_DIM),
        (__attribute__((address_space(3))) void*)(Bs + 2048 + wave * 512), 16, 0, 0);
    __syncthreads();

    bf16x8 fragA[4], fragB[4];
#pragma unroll
    for (int i = 0; i < 4; ++i)
      fragA[i] = *(const bf16x8*)(As + (wm * 64 + i * 16 + lrow) * BK + lquad * 8);
#pragma unroll
    for (int i = 0; i < 4; ++i)
      fragB[i] = *(const bf16x8*)(Bs + (wn * 64 + i * 16 + lrow) * BK + lquad * 8);
#pragma unroll
    for (int mi = 0; mi < 4; ++mi)
#pragma unroll
      for (int ni = 0; ni < 4; ++ni)
        acc[mi][ni] = __builtin_amdgcn_mfma_f32_16x16x32_bf16(
            fragA[mi], fragB[ni], acc[mi][ni], 0, 0, 0);
  }

  // Epilogue. C/D layout: col = lane&15, row = (lane>>4)*4 + reg.
#pragma unroll
  for (int ni = 0; ni < 4; ++ni) {
    const int colg = col0 + wn * 64 + ni * 16 + lrow;
    const float gv = g[colg];
    float s = 0.f;
#pragma unroll
    for (int mi = 0; mi < 4; ++mi) {
      const int rowg = row0 + wm * 64 + mi * 16 + lquad * 4;
#pragma unroll
      for (int r = 0; r < 4; ++r) {
        float f = sigmoidf(gv + acc[mi][ni][r]);
        s += f * cc[(size_t)(rowg + r) * H_DIM + colg];
      }
    }
    s += __shfl_xor(s, 16);
    s += __shfl_xor(s, 32);
    if (lquad == 0) atomicAdd(accv + colg, s);
  }
}

// ---------------------------------------------------------------------------
// Kernel D: finalize (fp32 out).  iou = [i|o|u]; c = sig(i)*tanh(u) + acc;
// h = sig(o)*tanh(c).  out = [sig(o) | c | h].
// ---------------------------------------------------------------------------
__global__ __launch_bounds__(256) void kfinal(const float* __restrict__ iou,
                                              const float* __restrict__ accv,
                                              float* __restrict__ out) {
  const int h = blockIdx.x * 256 + threadIdx.x;
  float si = sigmoidf(iou[h]);
  float so = sigmoidf(iou[H_DIM + h]);
  float tu = tanhf(iou[2 * H_DIM + h]);
  float c = si * tu + accv[h];
  float hh = so * tanhf(c);
  out[h] = so;
  out[H_DIM + h] = c;
  out[2 * H_DIM + h] = hh;
}

extern "C" void kernel_launch(void* const* d_in, const int* in_sizes, int n_in,
                              void* d_out, int out_size, void* d_ws, size_t ws_size,
                              hipStream_t stream) {
  const float* x   = (const float*)d_in[0];   // input [2048]
  const float* cc  = (const float*)d_in[1];   // children_c [4096,2048]
  const float* ch  = (const float*)d_in[2];   // children_h [4096,2048]
  const float* Wix = (const float*)d_in[3];   // W_iou_x [6144,2048]
  const float* bix = (const float*)d_in[4];   // b_iou_x [6144]
  const float* Wih = (const float*)d_in[5];   // W_iou_h [6144,2048]
  const float* bih = (const float*)d_in[6];   // b_iou_h [6144]
  const float* Wfx = (const float*)d_in[7];   // W_fx [2048,2048]
  const float* bfx = (const float*)d_in[8];   // b_fx [2048]
  const float* Wfh = (const float*)d_in[9];   // W_fh [2048,2048]
  const float* bfh = (const float*)d_in[10];  // b_fh [2048]

  float* ws   = (float*)d_ws;
  float* hsum = ws;                    // [2048]
  float* iou  = ws + 2048;             // [6144]
  float* g    = ws + 8192;             // [2048]
  float* accv = ws + 10240;            // [2048]
  float* partials = ws + 12288;        // [256 * 2048]
  u16* chb  = (u16*)(ws + 12288 + 256 * 2048);  // [4096*2048] bf16
  u16* wfhb = chb + (size_t)K_CH * H_DIM;       // [2048*2048] bf16
  float* out = (float*)d_out;

  hipMemsetAsync(accv, 0, 2048 * sizeof(float), stream);
  kprep<<<512, 256, 0, stream>>>(ch, Wfh, partials, chb, wfhb);
  kred<<<8, 256, 0, stream>>>(partials, hsum);
  kmatvec<<<2048, 256, 0, stream>>>(Wix, bix, Wih, bih, Wfx, bfx, bfh, x, hsum, iou, g);
  kgemm<<<dim3(32, 16), 256, 0, stream>>>(chb, cc, wfhb, g, accv);
  kfinal<<<8, 256, 0, stream>>>(iou, accv, out);
}